// Round 1
// baseline (423.003 us; speedup 1.0000x reference)
//
#include <hip/hip_runtime.h>

// TopKRouter: B=4,S=4096,D=4096,E=64,K=2 (tokens=16384)
// R4: LDS-staged split-bf16 MFMA pipeline.
//   - R3 was L2-transaction-bound (~2 GB L2 traffic: no staging, W re-read
//     per wave). R4 stages x (fp32) and W (pre-split bf16 hi/lo, fragment-
//     major) through LDS via global_load_lds(16B), triple-buffered.
//   - Raw `s_waitcnt vmcnt(4); s_barrier` keeps next tile's loads in flight
//     across the barrier (__syncthreads would drain vmcnt(0)).
//   - Block = 512 thr / 8 waves = 64 tok x 64 exp; wave = 16 tok x 32 exp
//     (2x mfma_f32_16x16x32_bf16, 3 MFMAs per chunk: hi*HI+lo*HI+hi*LO).
//   - x LDS layout XOR-swizzled (m ^ (tok&7)) at the *source* address so
//     A-frag ds_read_b128 is conflict-free (dest must be lane-contiguous).
// R5 (this round): unchanged resubmission — prior bench died on container
//   acquisition (infra), no counters. Need the profile before editing.

#define TOK 16384
#define DIM 4096
#define NE  64
#define BK  64
#define NT  (DIM / BK)           // 64 K-tiles
#define IDX_OFF (TOK * NE)
#define VAL_OFF (IDX_OFF + TOK * 2)

typedef __attribute__((ext_vector_type(8))) short short8;
typedef __attribute__((ext_vector_type(4))) float f32x4;
union pk8u { unsigned int u[4]; short8 s; };

__device__ __forceinline__ unsigned int pack_hi(float fa, float fb) {
    return __builtin_amdgcn_perm(__float_as_uint(fb), __float_as_uint(fa), 0x07060302u);
}
__device__ __forceinline__ unsigned int pack_lo(float fa, float fb) {
    float la = fa - __uint_as_float(__float_as_uint(fa) & 0xffff0000u);  // exact
    float lb = fb - __uint_as_float(__float_as_uint(fb) & 0xffff0000u);  // exact
    return __builtin_amdgcn_perm(__float_as_uint(lb), __float_as_uint(la), 0x07060302u);
}
__device__ __forceinline__ void split8(const float4 v0, const float4 v1,
                                       short8& hi, short8& lo) {
    pk8u h, l;
    h.u[0] = pack_hi(v0.x, v0.y); l.u[0] = pack_lo(v0.x, v0.y);
    h.u[1] = pack_hi(v0.z, v0.w); l.u[1] = pack_lo(v0.z, v0.w);
    h.u[2] = pack_hi(v1.x, v1.y); l.u[2] = pack_lo(v1.x, v1.y);
    h.u[3] = pack_hi(v1.z, v1.w); l.u[3] = pack_lo(v1.z, v1.w);
    hi = h.s; lo = l.s;
}

// W -> fragment-major packed bf16 hi/lo in ws.
// Unit layout: ws unit index r = t*16 + (c*8 + g*2 + h); within unit:
// lane l (0..63), 8 bf16 = W[e = g*16 + (l&15)][t*64 + c*32 + (l>>4)*8 + j]
__global__ __launch_bounds__(256)
void wconv_kernel(const float* __restrict__ W, unsigned short* __restrict__ ws) {
    const int gid = blockIdx.x * 256 + threadIdx.x;   // 0..65535
    const int l = gid & 63;
    const int r = gid >> 6;
    const int h = r & 1;
    const int g = (r >> 1) & 3;
    const int c = (r >> 3) & 1;
    const int t = r >> 4;                              // 0..63
    const int e = g * 16 + (l & 15);
    const int k = t * 64 + c * 32 + (l >> 4) * 8;
    const float4 va = *(const float4*)(W + (size_t)e * DIM + k);
    const float4 vb = *(const float4*)(W + (size_t)e * DIM + k + 4);
    pk8u o;
    if (h == 0) {                                      // wave-uniform branch
        o.u[0] = pack_hi(va.x, va.y); o.u[1] = pack_hi(va.z, va.w);
        o.u[2] = pack_hi(vb.x, vb.y); o.u[3] = pack_hi(vb.z, vb.w);
    } else {
        o.u[0] = pack_lo(va.x, va.y); o.u[1] = pack_lo(va.z, va.w);
        o.u[2] = pack_lo(vb.x, vb.y); o.u[3] = pack_lo(vb.z, vb.w);
    }
    ((uint4*)ws)[gid] = *(uint4*)&o.u[0];
}

__global__ __launch_bounds__(512)
void router_mfma(const float* __restrict__ x,
                 const unsigned short* __restrict__ wsg,
                 float* __restrict__ out)
{
    __shared__ __align__(16) float          xs[3 * 4096];   // 3 x 16 KB
    __shared__ __align__(16) unsigned short wls[3 * 8192];  // 3 x 16 KB
    __shared__ __align__(16) float          lgt[64 * 68];   // 17408 B

    const int tid  = threadIdx.x;
    const int lane = tid & 63;
    const int wid  = __builtin_amdgcn_readfirstlane(tid >> 6);
    const int t0   = blockIdx.x * 64;
    const int c16  = lane & 15;
    const int q    = lane >> 4;
    const int tp   = wid & 3;      // token position (16-row group)
    const int eh   = wid >> 2;     // expert half (g = eh*2 + g2)

    // stage tile tt into buffer b: 4 global_load_lds(16B) per wave
    auto issue = [&](int tt, int b) {
#pragma unroll
        for (int i = 0; i < 2; ++i) {                  // x units
            const int u   = wid * 2 + i;
            const int p   = u * 64 + lane;             // chunk id 0..1023
            const int tok = p >> 4;
            const int m   = (p & 15) ^ (tok & 7);      // XOR source swizzle
            const float* src = x + (size_t)(t0 + tok) * DIM + tt * BK + m * 4;
            __builtin_amdgcn_global_load_lds(
                (const __attribute__((address_space(1))) unsigned int*)src,
                (__attribute__((address_space(3))) unsigned int*)&xs[b * 4096 + u * 256],
                16, 0, 0);
        }
#pragma unroll
        for (int i = 0; i < 2; ++i) {                  // W units (frag-major, contiguous)
            const int v = wid * 2 + i;
            const unsigned short* src = wsg + ((size_t)(tt * 16 + v) * 64 + lane) * 8;
            __builtin_amdgcn_global_load_lds(
                (const __attribute__((address_space(1))) unsigned int*)src,
                (__attribute__((address_space(3))) unsigned int*)&wls[b * 8192 + v * 512],
                16, 0, 0);
        }
    };

    f32x4 acc0 = {0.f, 0.f, 0.f, 0.f};
    f32x4 acc1 = {0.f, 0.f, 0.f, 0.f};

    issue(0, 0);
    issue(1, 1);
    int b = 0;
    for (int t = 0; t < NT; ++t) {
        // wait only tile t's 4 loads (oldest); tile t+1's stay in flight
        if (t < NT - 1)
            asm volatile("s_waitcnt vmcnt(4) lgkmcnt(0)\n\ts_barrier" ::: "memory");
        else
            asm volatile("s_waitcnt vmcnt(0) lgkmcnt(0)\n\ts_barrier" ::: "memory");
        if (t + 2 < NT) issue(t + 2, (b + 2) % 3);     // into buffer of tile t-1 (free)

        const float*          xb = &xs[b * 4096];
        const unsigned short* wb = &wls[b * 8192];
#pragma unroll
        for (int c = 0; c < 2; ++c) {                  // 2 K=32 chunks
            const int tokA = tp * 16 + c16;
            const int m1   = c * 8 + q * 2;
            const float4 a0 = *(const float4*)(xb + (tokA * 16 + ( m1      ^ (tokA & 7))) * 4);
            const float4 a1 = *(const float4*)(xb + (tokA * 16 + ((m1 + 1) ^ (tokA & 7))) * 4);
            short8 ah, al;
            split8(a0, a1, ah, al);
#pragma unroll
            for (int g2 = 0; g2 < 2; ++g2) {
                const int g = eh * 2 + g2;
                const int vb_ = ((c * 4 + g) * 2) * 512 + lane * 8;
                const short8 bh = *(const short8*)(wb + vb_);
                const short8 bl = *(const short8*)(wb + vb_ + 512);
                f32x4& A = g2 ? acc1 : acc0;
                A = __builtin_amdgcn_mfma_f32_16x16x32_bf16(ah, bh, A, 0, 0, 0);
                A = __builtin_amdgcn_mfma_f32_16x16x32_bf16(al, bh, A, 0, 0, 0);
                A = __builtin_amdgcn_mfma_f32_16x16x32_bf16(ah, bl, A, 0, 0, 0);
            }
        }
        b = (b + 1) % 3;
    }

    // ---- epilogue: logits -> LDS, softmax + top-2 ----
    // C/D layout (m89-verified): col = lane&15 (expert in group), row = q*4+reg
#pragma unroll
    for (int r = 0; r < 4; ++r) {
        lgt[(tp * 16 + q * 4 + r) * 68 + (eh * 2 + 0) * 16 + c16] = acc0[r];
        lgt[(tp * 16 + q * 4 + r) * 68 + (eh * 2 + 1) * 16 + c16] = acc1[r];
    }
    __syncthreads();

    if (tid < 64) {
        const int tkn = t0 + tid;
        float* row = lgt + tid * 68;
        float m = -3.0e38f;
#pragma unroll
        for (int e4 = 0; e4 < NE; e4 += 4) {
            const float4 v = *(const float4*)(row + e4);
            m = fmaxf(m, fmaxf(fmaxf(v.x, v.y), fmaxf(v.z, v.w)));
        }
        float sum = 0.f, v1 = -3.0e38f, v2 = -3.0e38f;
        int i1 = 0, i2 = 0;
#pragma unroll
        for (int e4 = 0; e4 < NE; e4 += 4) {
            const float4 v = *(const float4*)(row + e4);
            sum += __expf(v.x - m) + __expf(v.y - m) + __expf(v.z - m) + __expf(v.w - m);
            const float* pv = &v.x;
#pragma unroll
            for (int j = 0; j < 4; ++j) {              // ascending e => lax.top_k tie-break
                const float p = pv[j];
                const int e = e4 + j;
                if (p > v1)      { v2 = v1; i2 = i1; v1 = p; i1 = e; }
                else if (p > v2) { v2 = p;  i2 = e; }
            }
        }
        const float inv = 1.f / sum;
        row[64] = m; row[65] = inv;
        out[IDX_OFF + (size_t)tkn * 2]     = (float)i1;
        out[IDX_OFF + (size_t)tkn * 2 + 1] = (float)i2;
        out[VAL_OFF + (size_t)tkn * 2]     = __expf(v1 - m) * inv;
        out[VAL_OFF + (size_t)tkn * 2 + 1] = __expf(v2 - m) * inv;
    }
    __syncthreads();

    {   // coalesced probs write: 512 threads x 8 floats = 64 tok x 64 exp
        const int row = tid >> 3;
        const int e8  = (tid & 7) * 8;
        const float m   = lgt[row * 68 + 64];
        const float inv = lgt[row * 68 + 65];
        const float4 v0 = *(const float4*)(lgt + row * 68 + e8);
        const float4 v1 = *(const float4*)(lgt + row * 68 + e8 + 4);
        float4 p0, p1;
        p0.x = __expf(v0.x - m) * inv; p0.y = __expf(v0.y - m) * inv;
        p0.z = __expf(v0.z - m) * inv; p0.w = __expf(v0.w - m) * inv;
        p1.x = __expf(v1.x - m) * inv; p1.y = __expf(v1.y - m) * inv;
        p1.z = __expf(v1.z - m) * inv; p1.w = __expf(v1.w - m) * inv;
        float* dst = out + (size_t)(t0 + row) * NE + e8;
        *(float4*)dst       = p0;
        *(float4*)(dst + 4) = p1;
    }
}

// correctness-only fallback if ws is too small (should not trigger)
__global__ __launch_bounds__(64)
void fallback_kernel(const float* __restrict__ x, const float* __restrict__ W,
                     float* __restrict__ out) {
    const int tk = blockIdx.x * 64 + threadIdx.x;
    const float* xr = x + (size_t)tk * DIM;
    float lg[NE];
    float m = -3.0e38f;
    for (int e = 0; e < NE; ++e) {
        const float* wr = W + (size_t)e * DIM;
        float s = 0.f;
        for (int d = 0; d < DIM; d += 4) {
            const float4 a = *(const float4*)(xr + d);
            const float4 bb = *(const float4*)(wr + d);
            s += a.x * bb.x + a.y * bb.y + a.z * bb.z + a.w * bb.w;
        }
        lg[e] = s; m = fmaxf(m, s);
    }
    float sum = 0.f;
    for (int e = 0; e < NE; ++e) sum += __expf(lg[e] - m);
    const float inv = 1.f / sum;
    float v1 = -3.0e38f, v2 = -3.0e38f; int i1 = 0, i2 = 0;
    for (int e = 0; e < NE; ++e) {
        const float p = __expf(lg[e] - m) * inv;
        out[(size_t)tk * NE + e] = p;
        if (p > v1)      { v2 = v1; i2 = i1; v1 = p; i1 = e; }
        else if (p > v2) { v2 = p;  i2 = e; }
    }
    out[IDX_OFF + (size_t)tk * 2]     = (float)i1;
    out[IDX_OFF + (size_t)tk * 2 + 1] = (float)i2;
    out[VAL_OFF + (size_t)tk * 2]     = v1;
    out[VAL_OFF + (size_t)tk * 2 + 1] = v2;
}

extern "C" void kernel_launch(void* const* d_in, const int* in_sizes, int n_in,
                              void* d_out, int out_size, void* d_ws, size_t ws_size,
                              hipStream_t stream) {
    const float* x = (const float*)d_in[0];
    const float* W = (const float*)d_in[1];
    float* out = (float*)d_out;
    (void)in_sizes; (void)n_in; (void)out_size;

    if (ws_size >= (size_t)NE * DIM * 2 * 2) {         // 1 MB hi+lo bf16
        wconv_kernel<<<256, 256, 0, stream>>>(W, (unsigned short*)d_ws);
        router_mfma<<<TOK / 64, 512, 0, stream>>>(x, (const unsigned short*)d_ws, out);
    } else {
        fallback_kernel<<<TOK / 64, 64, 0, stream>>>(x, W, out);
    }
}

// Round 3
// 395.045 us; speedup vs baseline: 1.0708x; 1.0708x over previous
//
#include <hip/hip_runtime.h>

// TopKRouter: B=4,S=4096,D=4096,E=64,K=2 (tokens=16384)
// R4: LDS-staged split-bf16 MFMA pipeline (triple-buffered, vmcnt(4)).
// R6: pipeline depth 3 -> 4 tiles.
//   Profile showed router at 170us = 6375 cyc/tile vs ~500 cyc compute:
//   delivery-rate-limited on x staging (1.58 TB/s effective, Little's law:
//   only 2 tiles / 64 KB per CU in flight). Depth-4 raises in-flight to
//   96 KB/CU (prefetch 3 ahead, wait vmcnt(8)). LDS = 4 x 32 KB = 128 KB;
//   epilogue lgt scratch aliased onto buffer 0 (free after tile 60).
//   - Block = 512 thr / 8 waves = 64 tok x 64 exp; wave = 16 tok x 32 exp
//     (2x mfma_f32_16x16x32_bf16, 3 MFMAs per chunk: hi*HI+lo*HI+hi*LO).
//   - x LDS layout XOR-swizzled (m ^ (tok&7)) at the *source* address so
//     A-frag ds_read_b128 is conflict-free (dest must be lane-contiguous).
// R7 (this round): unchanged resubmission — R6 bench died on container
//   acquisition (infra), no counters. Need the depth-4 profile before editing.

#define TOK 16384
#define DIM 4096
#define NE  64
#define BK  64
#define NT  (DIM / BK)           // 64 K-tiles
#define IDX_OFF (TOK * NE)
#define VAL_OFF (IDX_OFF + TOK * 2)

typedef __attribute__((ext_vector_type(8))) short short8;
typedef __attribute__((ext_vector_type(4))) float f32x4;
union pk8u { unsigned int u[4]; short8 s; };

__device__ __forceinline__ unsigned int pack_hi(float fa, float fb) {
    return __builtin_amdgcn_perm(__float_as_uint(fb), __float_as_uint(fa), 0x07060302u);
}
__device__ __forceinline__ unsigned int pack_lo(float fa, float fb) {
    float la = fa - __uint_as_float(__float_as_uint(fa) & 0xffff0000u);  // exact
    float lb = fb - __uint_as_float(__float_as_uint(fb) & 0xffff0000u);  // exact
    return __builtin_amdgcn_perm(__float_as_uint(lb), __float_as_uint(la), 0x07060302u);
}
__device__ __forceinline__ void split8(const float4 v0, const float4 v1,
                                       short8& hi, short8& lo) {
    pk8u h, l;
    h.u[0] = pack_hi(v0.x, v0.y); l.u[0] = pack_lo(v0.x, v0.y);
    h.u[1] = pack_hi(v0.z, v0.w); l.u[1] = pack_lo(v0.z, v0.w);
    h.u[2] = pack_hi(v1.x, v1.y); l.u[2] = pack_lo(v1.x, v1.y);
    h.u[3] = pack_hi(v1.z, v1.w); l.u[3] = pack_lo(v1.z, v1.w);
    hi = h.s; lo = l.s;
}

// W -> fragment-major packed bf16 hi/lo in ws.
// Unit layout: ws unit index r = t*16 + (c*8 + g*2 + h); within unit:
// lane l (0..63), 8 bf16 = W[e = g*16 + (l&15)][t*64 + c*32 + (l>>4)*8 + j]
__global__ __launch_bounds__(256)
void wconv_kernel(const float* __restrict__ W, unsigned short* __restrict__ ws) {
    const int gid = blockIdx.x * 256 + threadIdx.x;   // 0..65535
    const int l = gid & 63;
    const int r = gid >> 6;
    const int h = r & 1;
    const int g = (r >> 1) & 3;
    const int c = (r >> 3) & 1;
    const int t = r >> 4;                              // 0..63
    const int e = g * 16 + (l & 15);
    const int k = t * 64 + c * 32 + (l >> 4) * 8;
    const float4 va = *(const float4*)(W + (size_t)e * DIM + k);
    const float4 vb = *(const float4*)(W + (size_t)e * DIM + k + 4);
    pk8u o;
    if (h == 0) {                                      // wave-uniform branch
        o.u[0] = pack_hi(va.x, va.y); o.u[1] = pack_hi(va.z, va.w);
        o.u[2] = pack_hi(vb.x, vb.y); o.u[3] = pack_hi(vb.z, vb.w);
    } else {
        o.u[0] = pack_lo(va.x, va.y); o.u[1] = pack_lo(va.z, va.w);
        o.u[2] = pack_lo(vb.x, vb.y); o.u[3] = pack_lo(vb.z, vb.w);
    }
    ((uint4*)ws)[gid] = *(uint4*)&o.u[0];
}

__global__ __launch_bounds__(512)
void router_mfma(const float* __restrict__ x,
                 const unsigned short* __restrict__ wsg,
                 float* __restrict__ out)
{
    // 4 buffers x 32 KB: [x 16 KB][W 16 KB] each. lgt (17408 B) aliases buf 0.
    __shared__ __align__(16) unsigned char smem[4 * 32768];

    const int tid  = threadIdx.x;
    const int lane = tid & 63;
    const int wid  = __builtin_amdgcn_readfirstlane(tid >> 6);
    const int t0   = blockIdx.x * 64;
    const int c16  = lane & 15;
    const int q    = lane >> 4;
    const int tp   = wid & 3;      // token position (16-row group)
    const int eh   = wid >> 2;     // expert half (g = eh*2 + g2)

    // stage tile tt into buffer b: 4 global_load_lds(16B) per wave
    auto issue = [&](int tt, int b) {
        unsigned char* xbase = smem + b * 32768;
        unsigned char* wbase = smem + b * 32768 + 16384;
#pragma unroll
        for (int i = 0; i < 2; ++i) {                  // x units
            const int u   = wid * 2 + i;
            const int p   = u * 64 + lane;             // chunk id 0..1023
            const int tok = p >> 4;
            const int m   = (p & 15) ^ (tok & 7);      // XOR source swizzle
            const float* src = x + (size_t)(t0 + tok) * DIM + tt * BK + m * 4;
            __builtin_amdgcn_global_load_lds(
                (const __attribute__((address_space(1))) unsigned int*)src,
                (__attribute__((address_space(3))) unsigned int*)(xbase + u * 1024),
                16, 0, 0);
        }
#pragma unroll
        for (int i = 0; i < 2; ++i) {                  // W units (frag-major, contiguous)
            const int v = wid * 2 + i;
            const unsigned short* src = wsg + ((size_t)(tt * 16 + v) * 64 + lane) * 8;
            __builtin_amdgcn_global_load_lds(
                (const __attribute__((address_space(1))) unsigned int*)src,
                (__attribute__((address_space(3))) unsigned int*)(wbase + v * 1024),
                16, 0, 0);
        }
    };

    f32x4 acc0 = {0.f, 0.f, 0.f, 0.f};
    f32x4 acc1 = {0.f, 0.f, 0.f, 0.f};

    issue(0, 0);
    issue(1, 1);
    issue(2, 2);
    int b = 0;
    for (int t = 0; t < NT; ++t) {
        // wait only tile t's 4 loads (oldest of 12); t+1/t+2 stay in flight
        if (t < NT - 2)
            asm volatile("s_waitcnt vmcnt(8) lgkmcnt(0)\n\ts_barrier" ::: "memory");
        else if (t == NT - 2)
            asm volatile("s_waitcnt vmcnt(4) lgkmcnt(0)\n\ts_barrier" ::: "memory");
        else
            asm volatile("s_waitcnt vmcnt(0) lgkmcnt(0)\n\ts_barrier" ::: "memory");
        if (t + 3 < NT) issue(t + 3, (b + 3) & 3);     // into buffer of tile t-1 (free)

        const float*          xb = (const float*)(smem + b * 32768);
        const unsigned short* wb = (const unsigned short*)(smem + b * 32768 + 16384);
#pragma unroll
        for (int c = 0; c < 2; ++c) {                  // 2 K=32 chunks
            const int tokA = tp * 16 + c16;
            const int m1   = c * 8 + q * 2;
            const float4 a0 = *(const float4*)(xb + (tokA * 16 + ( m1      ^ (tokA & 7))) * 4);
            const float4 a1 = *(const float4*)(xb + (tokA * 16 + ((m1 + 1) ^ (tokA & 7))) * 4);
            short8 ah, al;
            split8(a0, a1, ah, al);
#pragma unroll
            for (int g2 = 0; g2 < 2; ++g2) {
                const int g = eh * 2 + g2;
                const int vb_ = ((c * 4 + g) * 2) * 512 + lane * 8;
                const short8 bh = *(const short8*)(wb + vb_);
                const short8 bl = *(const short8*)(wb + vb_ + 512);
                f32x4& A = g2 ? acc1 : acc0;
                A = __builtin_amdgcn_mfma_f32_16x16x32_bf16(ah, bh, A, 0, 0, 0);
                A = __builtin_amdgcn_mfma_f32_16x16x32_bf16(al, bh, A, 0, 0, 0);
                A = __builtin_amdgcn_mfma_f32_16x16x32_bf16(ah, bl, A, 0, 0, 0);
            }
        }
        b = (b + 1) & 3;
    }

    // ---- epilogue: logits -> LDS (aliases buffer 0; free since tile 60),
    //      softmax + top-2 ----
    // C/D layout (m89-verified): col = lane&15 (expert in group), row = q*4+reg
    float* lgt = (float*)smem;
#pragma unroll
    for (int r = 0; r < 4; ++r) {
        lgt[(tp * 16 + q * 4 + r) * 68 + (eh * 2 + 0) * 16 + c16] = acc0[r];
        lgt[(tp * 16 + q * 4 + r) * 68 + (eh * 2 + 1) * 16 + c16] = acc1[r];
    }
    __syncthreads();

    if (tid < 64) {
        const int tkn = t0 + tid;
        float* row = lgt + tid * 68;
        float m = -3.0e38f;
#pragma unroll
        for (int e4 = 0; e4 < NE; e4 += 4) {
            const float4 v = *(const float4*)(row + e4);
            m = fmaxf(m, fmaxf(fmaxf(v.x, v.y), fmaxf(v.z, v.w)));
        }
        float sum = 0.f, v1 = -3.0e38f, v2 = -3.0e38f;
        int i1 = 0, i2 = 0;
#pragma unroll
        for (int e4 = 0; e4 < NE; e4 += 4) {
            const float4 v = *(const float4*)(row + e4);
            sum += __expf(v.x - m) + __expf(v.y - m) + __expf(v.z - m) + __expf(v.w - m);
            const float* pv = &v.x;
#pragma unroll
            for (int j = 0; j < 4; ++j) {              // ascending e => lax.top_k tie-break
                const float p = pv[j];
                const int e = e4 + j;
                if (p > v1)      { v2 = v1; i2 = i1; v1 = p; i1 = e; }
                else if (p > v2) { v2 = p;  i2 = e; }
            }
        }
        const float inv = 1.f / sum;
        row[64] = m; row[65] = inv;
        out[IDX_OFF + (size_t)tkn * 2]     = (float)i1;
        out[IDX_OFF + (size_t)tkn * 2 + 1] = (float)i2;
        out[VAL_OFF + (size_t)tkn * 2]     = __expf(v1 - m) * inv;
        out[VAL_OFF + (size_t)tkn * 2 + 1] = __expf(v2 - m) * inv;
    }
    __syncthreads();

    {   // coalesced probs write: 512 threads x 8 floats = 64 tok x 64 exp
        const int row = tid >> 3;
        const int e8  = (tid & 7) * 8;
        const float m   = lgt[row * 68 + 64];
        const float inv = lgt[row * 68 + 65];
        const float4 v0 = *(const float4*)(lgt + row * 68 + e8);
        const float4 v1 = *(const float4*)(lgt + row * 68 + e8 + 4);
        float4 p0, p1;
        p0.x = __expf(v0.x - m) * inv; p0.y = __expf(v0.y - m) * inv;
        p0.z = __expf(v0.z - m) * inv; p0.w = __expf(v0.w - m) * inv;
        p1.x = __expf(v1.x - m) * inv; p1.y = __expf(v1.y - m) * inv;
        p1.z = __expf(v1.z - m) * inv; p1.w = __expf(v1.w - m) * inv;
        float* dst = out + (size_t)(t0 + row) * NE + e8;
        *(float4*)dst       = p0;
        *(float4*)(dst + 4) = p1;
    }
}

// correctness-only fallback if ws is too small (should not trigger)
__global__ __launch_bounds__(64)
void fallback_kernel(const float* __restrict__ x, const float* __restrict__ W,
                     float* __restrict__ out) {
    const int tk = blockIdx.x * 64 + threadIdx.x;
    const float* xr = x + (size_t)tk * DIM;
    float lg[NE];
    float m = -3.0e38f;
    for (int e = 0; e < NE; ++e) {
        const float* wr = W + (size_t)e * DIM;
        float s = 0.f;
        for (int d = 0; d < DIM; d += 4) {
            const float4 a = *(const float4*)(xr + d);
            const float4 bb = *(const float4*)(wr + d);
            s += a.x * bb.x + a.y * bb.y + a.z * bb.z + a.w * bb.w;
        }
        lg[e] = s; m = fmaxf(m, s);
    }
    float sum = 0.f;
    for (int e = 0; e < NE; ++e) sum += __expf(lg[e] - m);
    const float inv = 1.f / sum;
    float v1 = -3.0e38f, v2 = -3.0e38f; int i1 = 0, i2 = 0;
    for (int e = 0; e < NE; ++e) {
        const float p = __expf(lg[e] - m) * inv;
        out[(size_t)tk * NE + e] = p;
        if (p > v1)      { v2 = v1; i2 = i1; v1 = p; i1 = e; }
        else if (p > v2) { v2 = p;  i2 = e; }
    }
    out[IDX_OFF + (size_t)tk * 2]     = (float)i1;
    out[IDX_OFF + (size_t)tk * 2 + 1] = (float)i2;
    out[VAL_OFF + (size_t)tk * 2]     = v1;
    out[VAL_OFF + (size_t)tk * 2 + 1] = v2;
}

extern "C" void kernel_launch(void* const* d_in, const int* in_sizes, int n_in,
                              void* d_out, int out_size, void* d_ws, size_t ws_size,
                              hipStream_t stream) {
    const float* x = (const float*)d_in[0];
    const float* W = (const float*)d_in[1];
    float* out = (float*)d_out;
    (void)in_sizes; (void)n_in; (void)out_size;

    if (ws_size >= (size_t)NE * DIM * 2 * 2) {         // 1 MB hi+lo bf16
        wconv_kernel<<<256, 256, 0, stream>>>(W, (unsigned short*)d_ws);
        router_mfma<<<TOK / 64, 512, 0, stream>>>(x, (const unsigned short*)d_ws, out);
    } else {
        fallback_kernel<<<TOK / 64, 64, 0, stream>>>(x, W, out);
    }
}